// Round 6
// baseline (717.471 us; speedup 1.0000x reference)
//
#include <hip/hip_runtime.h>
#include <hip/hip_bf16.h>
#include <stdint.h>

#define T_TOK 4096
#define H_DIM 2048
#define I_DIM 1024
#define NEXP  16
#define NROWS 16384

typedef short bf16x8 __attribute__((ext_vector_type(8)));
typedef float f32x4  __attribute__((ext_vector_type(4)));
typedef unsigned short u16;

__device__ __forceinline__ u16 f2b(float f) {
  union { __hip_bfloat16 h; u16 u; } cv;
  cv.h = __float2bfloat16(f);
  return cv.u;
}

__device__ __forceinline__ void gload16(const void* g, void* l) {
  __builtin_amdgcn_global_load_lds((const __attribute__((address_space(1))) void*)g,
                                   (__attribute__((address_space(3))) void*)l, 16, 0, 0);
}

// ---------------- fp32 -> bf16 conversion ----------------
__global__ __launch_bounds__(256) void cvt4_kernel(const float4* __restrict__ src,
                                                   ushort4* __restrict__ dst, int n4) {
  int i = blockIdx.x * 256 + threadIdx.x;
  int stride = gridDim.x * 256;
  for (; i < n4; i += stride) {
    float4 v = src[i];
    ushort4 o;
    o.x = f2b(v.x); o.y = f2b(v.y); o.z = f2b(v.z); o.w = f2b(v.w);
    dst[i] = o;
  }
}

// ---------------- router: fp64 logits, top-2, renormalized weights ----------------
__global__ __launch_bounds__(256) void router_kernel(const float* __restrict__ x,
                                                     const float* __restrict__ gw,
                                                     int* __restrict__ sel,
                                                     float* __restrict__ selw,
                                                     int* __restrict__ counts) {
  int t = blockIdx.x;
  int tid = threadIdx.x;
  const float* xr = x + (size_t)t * H_DIM;
  double p[NEXP];
#pragma unroll
  for (int e = 0; e < NEXP; ++e) p[e] = 0.0;
#pragma unroll
  for (int j = 0; j < 8; ++j) {
    int h = tid * 8 + j;
    double xv = (double)xr[h];
#pragma unroll
    for (int e = 0; e < NEXP; ++e) p[e] += xv * (double)gw[e * H_DIM + h];
  }
#pragma unroll
  for (int e = 0; e < NEXP; ++e) {
#pragma unroll
    for (int off = 32; off > 0; off >>= 1) p[e] += __shfl_down(p[e], off);
  }
  __shared__ double sm[4][NEXP];
  int w = tid >> 6;
  if ((tid & 63) == 0) {
#pragma unroll
    for (int e = 0; e < NEXP; ++e) sm[w][e] = p[e];
  }
  __syncthreads();
  if (tid == 0) {
    double l0 = -1e300, l1 = -1e300;
    int e0 = 0, e1 = 0;
    for (int e = 0; e < NEXP; ++e) {
      double v = sm[0][e] + sm[1][e] + sm[2][e] + sm[3][e];
      if (v > l0) { l1 = l0; e1 = e0; l0 = v; e0 = e; }
      else if (v > l1) { l1 = v; e1 = e; }
    }
    double w0 = 1.0 / (1.0 + exp(l1 - l0));
    sel[t * 2 + 0] = e0;
    sel[t * 2 + 1] = e1;
    selw[t * 2 + 0] = (float)w0;
    selw[t * 2 + 1] = (float)(1.0 - w0);
    atomicAdd(&counts[e0], 1);
    atomicAdd(&counts[e1], 1);
  }
}

// ---------------- prefix: 256-aligned per-expert row bases ----------------
__global__ void prefix_kernel(const int* __restrict__ counts, int* __restrict__ rowbase) {
  if (threadIdx.x == 0 && blockIdx.x == 0) {
    int acc = 0;
    for (int e = 0; e < NEXP; ++e) {
      rowbase[e] = acc;
      acc += (counts[e] + 255) & ~255;
    }
    rowbase[NEXP] = acc;  // shared-expert base (dynamic)
  }
}

// ---------------- scatter tokens into packed per-expert row lists ----------------
__global__ __launch_bounds__(256) void scatter_kernel(const int* __restrict__ sel,
                                                      const float* __restrict__ selw,
                                                      const int* __restrict__ rowbase,
                                                      int* __restrict__ cursor,
                                                      int* __restrict__ tok_of_row,
                                                      float* __restrict__ coef_of_row) {
  int idx = blockIdx.x * 256 + threadIdx.x;
  if (idx < T_TOK * 2) {
    int t = idx >> 1;
    int e = sel[idx];
    int slot = atomicAdd(&cursor[e], 1);
    int row = rowbase[e] + slot;
    tok_of_row[row] = t;
    coef_of_row[row] = selw[idx];
  } else if (idx < T_TOK * 3) {
    int t = idx - T_TOK * 2;
    int sb = rowbase[NEXP];
    tok_of_row[sb + t] = t;
    coef_of_row[sb + t] = 1.0f;
  }
}

// =================================================================
// Pipelined grouped GEMM: 512 thr / 8 waves (2M x 4N), BM=256 BN=256 BK=32.
// Per-wave 128x64 output (MFMA:LDS-byte ratio 42.7 -> compute-bound).
// 3-buffer LDS pipeline (96 KB), counted vmcnt(4), raw s_barrier (1/tile),
// T2 swizzle for BK=32: byte koff ^= ((row>>1)&3)<<4  (2-way = free),
// T5 setprio.  Chunk c (8 shorts): row = c>>2, slot = c&3.
// =================================================================

// ---------------- GEMM1: gathered x @ w1e^T + b1e, fused SiLU*mul -> abuf ----------------
// B tile rows interleaved: even LDS row r -> gate col nt*128+r/2, odd -> up col.
__global__ __launch_bounds__(512, 1) void gemm1_kernel(
    const u16* __restrict__ x_bf, const u16* __restrict__ W1cat,
    const float* __restrict__ b1, const float* __restrict__ sg_b,
    const int* __restrict__ tok_of_row, const int* __restrict__ counts,
    const int* __restrict__ rowbase, u16* __restrict__ abuf) {
  int nt = blockIdx.x, rt = blockIdx.y, e = blockIdx.z;
  int n_e = (e < NEXP) ? counts[e] : T_TOK;
  if (rt * 256 >= n_e) return;
  int rbase = rowbase[e];
  int n_valid = n_e - rt * 256;
  if (n_valid > 256) n_valid = 256;

  __shared__ short As[3][8192];  // 256 rows x 32 k, swizzled
  __shared__ short Bs[3][8192];  // 256 rows x 32 k, swizzled
  __shared__ int Ts[256];

  int tid = threadIdx.x;
  if (tid < 256) Ts[tid] = tok_of_row[rbase + rt * 256 + tid];
  __syncthreads();

  // A: 1024 chunks (2 rounds x 512 thr); chunk c -> row=c>>2, koff=((c&3)*8)^(((row>>1)&3)<<3) shorts
  const u16* srcA[2];
  short* dstA[2];
#pragma unroll
  for (int p = 0; p < 2; ++p) {
    int c = p * 512 + tid;
    int r = c >> 2;
    int koff = ((c & 3) * 8) ^ (((r >> 1) & 3) << 3);
    int tok = Ts[r]; if (tok < 0) tok = 0;
    srcA[p] = x_bf + (size_t)tok * H_DIM + koff;
    dstA[p] = &As[0][(p * 512 + (tid & 0x1C0)) * 8];  // + lane*8 shorts by HW -> c*8
  }
  // B: 1024 chunks (2 rounds x 512 thr)
  const u16* srcB[2];
  short* dstB[2];
#pragma unroll
  for (int p = 0; p < 2; ++p) {
    int c = p * 512 + tid;
    int r = c >> 2;
    int koff = ((c & 3) * 8) ^ (((r >> 1) & 3) << 3);
    int gr = (r & 1) ? (I_DIM + nt * 128 + (r >> 1)) : (nt * 128 + (r >> 1));
    srcB[p] = W1cat + ((size_t)e * (2 * I_DIM) + gr) * H_DIM + koff;
    dstB[p] = &Bs[0][(p * 512 + (tid & 0x1C0)) * 8];
  }

  f32x4 acc[8][4];
#pragma unroll
  for (int m = 0; m < 8; ++m)
#pragma unroll
    for (int n = 0; n < 4; ++n) acc[m][n] = (f32x4){0.f, 0.f, 0.f, 0.f};

  int lane = tid & 63, w = tid >> 6, wr = w >> 2, wc = w & 3;
  int laneq = lane & 15, hi = lane >> 4;

  auto STAGE = [&](int buf) {
#pragma unroll
    for (int p = 0; p < 2; ++p) { gload16(srcA[p], dstA[p] + buf * 8192); srcA[p] += 32; }
#pragma unroll
    for (int p = 0; p < 2; ++p) { gload16(srcB[p], dstB[p] + buf * 8192); srcB[p] += 32; }
  };
  auto COMPUTE = [&](int buf) {
    const short* Ab = &As[buf][0];
    const short* Bb = &Bs[buf][0];
    bf16x8 b[4];
#pragma unroll
    for (int fn = 0; fn < 4; ++fn) {
      int row = wc * 64 + fn * 16 + laneq;
      b[fn] = *(const bf16x8*)(Bb + row * 32 + ((hi * 8) ^ (((row >> 1) & 3) << 3)));
    }
#pragma unroll
    for (int half = 0; half < 2; ++half) {
      bf16x8 a[4];
#pragma unroll
      for (int f = 0; f < 4; ++f) {
        int row = wr * 128 + (half * 4 + f) * 16 + laneq;
        a[f] = *(const bf16x8*)(Ab + row * 32 + ((hi * 8) ^ (((row >> 1) & 3) << 3)));
      }
      __builtin_amdgcn_s_setprio(1);
#pragma unroll
      for (int f = 0; f < 4; ++f)
#pragma unroll
        for (int fn = 0; fn < 4; ++fn)
          acc[half * 4 + f][fn] = __builtin_amdgcn_mfma_f32_16x16x32_bf16(
              a[f], b[fn], acc[half * 4 + f][fn], 0, 0, 0);
      __builtin_amdgcn_s_setprio(0);
    }
  };

  const int NT = H_DIM / 32;  // 64
  STAGE(0);
  STAGE(1);
  asm volatile("s_waitcnt vmcnt(4)" ::: "memory");
  __builtin_amdgcn_s_barrier();

  int cur = 0;
  for (int t = 0; t < NT - 2; ++t) {
    int nxt2 = cur + 2; if (nxt2 >= 3) nxt2 -= 3;
    STAGE(nxt2);          // writes buffer freed by previous barrier
    COMPUTE(cur);
    asm volatile("s_waitcnt vmcnt(4)" ::: "memory");  // tile t+1 landed; t+2 still flying
    __builtin_amdgcn_s_barrier();
    cur = (cur == 2) ? 0 : cur + 1;
  }
  COMPUTE(cur);
  asm volatile("s_waitcnt vmcnt(0)" ::: "memory");
  __builtin_amdgcn_s_barrier();
  cur = (cur == 2) ? 0 : cur + 1;
  COMPUTE(cur);

  // epilogue: pair g (even lane) with u (odd lane) via shfl_xor(1)
  const float* bias = (e < NEXP) ? (b1 + (size_t)e * (2 * I_DIM)) : sg_b;
  bool evenl = !(lane & 1);
  float bs[4];
#pragma unroll
  for (int nf = 0; nf < 4; ++nf) {
    int c = wc * 64 + nf * 16 + laneq;
    int j = c >> 1;
    bs[nf] = evenl ? bias[nt * 128 + j] : bias[I_DIM + nt * 128 + j];
  }
#pragma unroll
  for (int mf = 0; mf < 8; ++mf) {
#pragma unroll
    for (int nf = 0; nf < 4; ++nf) {
      int j = (wc * 64 + nf * 16 + laneq) >> 1;
#pragma unroll
      for (int reg = 0; reg < 4; ++reg) {
        int r = wr * 128 + mf * 16 + hi * 4 + reg;
        float v = acc[mf][nf][reg] + bs[nf];
        float o = __shfl_xor(v, 1);
        if (evenl && r < n_valid) {
          float g = v, u = o;
          float s = g / (1.0f + __expf(-g));
          abuf[(size_t)(rbase + rt * 256 + r) * I_DIM + nt * 128 + j] = f2b(s * u);
        }
      }
    }
  }
}

// ---------------- GEMM2: abuf @ w2e^T * coef -> out ----------------
template <int ATOMIC>
__global__ __launch_bounds__(512, 1) void gemm2_kernel(
    const u16* __restrict__ abuf, const u16* __restrict__ W2cat,
    const int* __restrict__ tok_of_row, const float* __restrict__ coef_of_row,
    const int* __restrict__ counts, const int* __restrict__ rowbase,
    float* __restrict__ out, int e_force) {
  int nt = blockIdx.x, rt = blockIdx.y;
  int e = (e_force >= 0) ? e_force : (int)blockIdx.z;
  int n_e = (e < NEXP) ? counts[e] : T_TOK;
  if (rt * 256 >= n_e) return;
  int rbase = rowbase[e];
  int n_valid = n_e - rt * 256;
  if (n_valid > 256) n_valid = 256;

  __shared__ short As[3][8192];
  __shared__ short Bs[3][8192];
  __shared__ int Ts[256];
  __shared__ float Cs[256];

  int tid = threadIdx.x;
  if (tid < 256) {
    int row = rbase + rt * 256 + tid;
    Ts[tid] = tok_of_row[row];
    Cs[tid] = coef_of_row[row];
  }
  __syncthreads();

  const u16* srcA[2];
  short* dstA[2];
#pragma unroll
  for (int p = 0; p < 2; ++p) {
    int c = p * 512 + tid;
    int r = c >> 2;
    int koff = ((c & 3) * 8) ^ (((r >> 1) & 3) << 3);
    srcA[p] = abuf + (size_t)(rbase + rt * 256 + r) * I_DIM + koff;
    dstA[p] = &As[0][(p * 512 + (tid & 0x1C0)) * 8];
  }
  const u16* srcB[2];
  short* dstB[2];
#pragma unroll
  for (int p = 0; p < 2; ++p) {
    int c = p * 512 + tid;
    int r = c >> 2;
    int koff = ((c & 3) * 8) ^ (((r >> 1) & 3) << 3);
    srcB[p] = W2cat + ((size_t)e * H_DIM + nt * 256 + r) * I_DIM + koff;
    dstB[p] = &Bs[0][(p * 512 + (tid & 0x1C0)) * 8];
  }

  f32x4 acc[8][4];
#pragma unroll
  for (int m = 0; m < 8; ++m)
#pragma unroll
    for (int n = 0; n < 4; ++n) acc[m][n] = (f32x4){0.f, 0.f, 0.f, 0.f};

  int lane = tid & 63, w = tid >> 6, wr = w >> 2, wc = w & 3;
  int laneq = lane & 15, hi = lane >> 4;

  auto STAGE = [&](int buf) {
#pragma unroll
    for (int p = 0; p < 2; ++p) { gload16(srcA[p], dstA[p] + buf * 8192); srcA[p] += 32; }
#pragma unroll
    for (int p = 0; p < 2; ++p) { gload16(srcB[p], dstB[p] + buf * 8192); srcB[p] += 32; }
  };
  auto COMPUTE = [&](int buf) {
    const short* Ab = &As[buf][0];
    const short* Bb = &Bs[buf][0];
    bf16x8 b[4];
#pragma unroll
    for (int fn = 0; fn < 4; ++fn) {
      int row = wc * 64 + fn * 16 + laneq;
      b[fn] = *(const bf16x8*)(Bb + row * 32 + ((hi * 8) ^ (((row >> 1) & 3) << 3)));
    }
#pragma unroll
    for (int half = 0; half < 2; ++half) {
      bf16x8 a[4];
#pragma unroll
      for (int f = 0; f < 4; ++f) {
        int row = wr * 128 + (half * 4 + f) * 16 + laneq;
        a[f] = *(const bf16x8*)(Ab + row * 32 + ((hi * 8) ^ (((row >> 1) & 3) << 3)));
      }
      __builtin_amdgcn_s_setprio(1);
#pragma unroll
      for (int f = 0; f < 4; ++f)
#pragma unroll
        for (int fn = 0; fn < 4; ++fn)
          acc[half * 4 + f][fn] = __builtin_amdgcn_mfma_f32_16x16x32_bf16(
              a[f], b[fn], acc[half * 4 + f][fn], 0, 0, 0);
      __builtin_amdgcn_s_setprio(0);
    }
  };

  const int NT = I_DIM / 32;  // 32
  STAGE(0);
  STAGE(1);
  asm volatile("s_waitcnt vmcnt(4)" ::: "memory");
  __builtin_amdgcn_s_barrier();

  int cur = 0;
  for (int t = 0; t < NT - 2; ++t) {
    int nxt2 = cur + 2; if (nxt2 >= 3) nxt2 -= 3;
    STAGE(nxt2);
    COMPUTE(cur);
    asm volatile("s_waitcnt vmcnt(4)" ::: "memory");
    __builtin_amdgcn_s_barrier();
    cur = (cur == 2) ? 0 : cur + 1;
  }
  COMPUTE(cur);
  asm volatile("s_waitcnt vmcnt(0)" ::: "memory");
  __builtin_amdgcn_s_barrier();
  cur = (cur == 2) ? 0 : cur + 1;
  COMPUTE(cur);

#pragma unroll
  for (int mf = 0; mf < 8; ++mf) {
#pragma unroll
    for (int nf = 0; nf < 4; ++nf) {
      int col = nt * 256 + wc * 64 + nf * 16 + laneq;
#pragma unroll
      for (int reg = 0; reg < 4; ++reg) {
        int r = wr * 128 + mf * 16 + hi * 4 + reg;
        if (r < n_valid) {
          int tok = Ts[r];
          float val = acc[mf][nf][reg] * Cs[r];
          float* p = out + (size_t)tok * H_DIM + col;
          if (ATOMIC) atomicAdd(p, val);
          else *p = val;
        }
      }
    }
  }
}

// ---------------- launch ----------------
extern "C" void kernel_launch(void* const* d_in, const int* in_sizes, int n_in,
                              void* d_out, int out_size, void* d_ws, size_t ws_size,
                              hipStream_t stream) {
  const float* x    = (const float*)d_in[0];
  const float* gate_w = (const float*)d_in[1];
  const float* w1   = (const float*)d_in[2];
  const float* b1   = (const float*)d_in[3];
  const float* w2   = (const float*)d_in[4];
  const float* sg_w = (const float*)d_in[5];
  const float* sg_b = (const float*)d_in[6];
  const float* sd_w = (const float*)d_in[7];
  float* out = (float*)d_out;

  uint8_t* ws = (uint8_t*)d_ws;
  size_t off = 0;
  auto alloc = [&](size_t bytes) -> void* {
    void* p = ws + off;
    off += (bytes + 255) & ~(size_t)255;
    return p;
  };
  u16*  W1cat = (u16*)alloc((size_t)17 * 2048 * 2048 * 2);
  u16*  W2cat = (u16*)alloc((size_t)17 * 2048 * 1024 * 2);
  u16*  x_bf  = (u16*)alloc((size_t)T_TOK * H_DIM * 2);
  u16*  abuf  = (u16*)alloc((size_t)NROWS * I_DIM * 2);
  int*  tok_of_row  = (int*)alloc((size_t)NROWS * 4);
  float* coef_of_row = (float*)alloc((size_t)NROWS * 4);
  int*  sel   = (int*)alloc((size_t)T_TOK * 2 * 4);
  float* selw = (float*)alloc((size_t)T_TOK * 2 * 4);
  int*  counts  = (int*)alloc(256);
  int*  cursor  = (int*)alloc(256);
  int*  rowbase = (int*)alloc(256);
  (void)ws_size; (void)in_sizes; (void)n_in; (void)out_size;

  hipMemsetAsync(counts, 0, 768, stream);                       // counts+cursor+rowbase
  hipMemsetAsync(tok_of_row, 0xFF, (size_t)NROWS * 4, stream);  // -1 = pad row

  auto cvt = [&](const float* s, u16* d, size_t n) {
    int n4 = (int)(n / 4);
    int blocks = (n4 + 255) / 256;
    if (blocks > 2048) blocks = 2048;
    cvt4_kernel<<<dim3(blocks), dim3(256), 0, stream>>>((const float4*)s, (ushort4*)d, n4);
  };
  cvt(w1,   W1cat, (size_t)16 * 2048 * 2048);
  cvt(sg_w, W1cat + (size_t)16 * 2048 * 2048, (size_t)2048 * 2048);
  cvt(w2,   W2cat, (size_t)16 * 2048 * 1024);
  cvt(sd_w, W2cat + (size_t)16 * 2048 * 1024, (size_t)2048 * 1024);
  cvt(x,    x_bf, (size_t)T_TOK * H_DIM);

  router_kernel<<<dim3(T_TOK), dim3(256), 0, stream>>>(x, gate_w, sel, selw, counts);
  prefix_kernel<<<dim3(1), dim3(64), 0, stream>>>(counts, rowbase);
  scatter_kernel<<<dim3(48), dim3(256), 0, stream>>>(sel, selw, rowbase, cursor, tok_of_row, coef_of_row);

  gemm1_kernel<<<dim3(8, 16, 17), dim3(512), 0, stream>>>(
      x_bf, W1cat, b1, sg_b, tok_of_row, counts, rowbase, abuf);

  // shared expert first: plain stores cover every out element, then routed experts atomicAdd
  gemm2_kernel<0><<<dim3(8, 16, 1), dim3(512), 0, stream>>>(
      abuf, W2cat, tok_of_row, coef_of_row, counts, rowbase, out, NEXP);
  gemm2_kernel<1><<<dim3(8, 16, 16), dim3(512), 0, stream>>>(
      abuf, W2cat, tok_of_row, coef_of_row, counts, rowbase, out, -1);
}

// Round 7
// 540.828 us; speedup vs baseline: 1.3266x; 1.3266x over previous
//
#include <hip/hip_runtime.h>
#include <hip/hip_bf16.h>
#include <stdint.h>

#define T_TOK 4096
#define H_DIM 2048
#define I_DIM 1024
#define NEXP  16
#define NROWS 16384

typedef short bf16x8 __attribute__((ext_vector_type(8)));
typedef float f32x4  __attribute__((ext_vector_type(4)));
typedef unsigned short u16;

__device__ __forceinline__ u16 f2b(float f) {
  union { __hip_bfloat16 h; u16 u; } cv;
  cv.h = __float2bfloat16(f);
  return cv.u;
}

__device__ __forceinline__ void gload16(const void* g, void* l) {
  __builtin_amdgcn_global_load_lds((const __attribute__((address_space(1))) void*)g,
                                   (__attribute__((address_space(3))) void*)l, 16, 0, 0);
}

// ---------------- fp32 -> bf16 conversion ----------------
__global__ __launch_bounds__(256) void cvt4_kernel(const float4* __restrict__ src,
                                                   ushort4* __restrict__ dst, int n4) {
  int i = blockIdx.x * 256 + threadIdx.x;
  int stride = gridDim.x * 256;
  for (; i < n4; i += stride) {
    float4 v = src[i];
    ushort4 o;
    o.x = f2b(v.x); o.y = f2b(v.y); o.z = f2b(v.z); o.w = f2b(v.w);
    dst[i] = o;
  }
}

// ---------------- router: fp64 logits, top-2, renormalized weights ----------------
__global__ __launch_bounds__(256) void router_kernel(const float* __restrict__ x,
                                                     const float* __restrict__ gw,
                                                     int* __restrict__ sel,
                                                     float* __restrict__ selw,
                                                     int* __restrict__ counts) {
  int t = blockIdx.x;
  int tid = threadIdx.x;
  const float* xr = x + (size_t)t * H_DIM;
  double p[NEXP];
#pragma unroll
  for (int e = 0; e < NEXP; ++e) p[e] = 0.0;
#pragma unroll
  for (int j = 0; j < 8; ++j) {
    int h = tid * 8 + j;
    double xv = (double)xr[h];
#pragma unroll
    for (int e = 0; e < NEXP; ++e) p[e] += xv * (double)gw[e * H_DIM + h];
  }
#pragma unroll
  for (int e = 0; e < NEXP; ++e) {
#pragma unroll
    for (int off = 32; off > 0; off >>= 1) p[e] += __shfl_down(p[e], off);
  }
  __shared__ double sm[4][NEXP];
  int w = tid >> 6;
  if ((tid & 63) == 0) {
#pragma unroll
    for (int e = 0; e < NEXP; ++e) sm[w][e] = p[e];
  }
  __syncthreads();
  if (tid == 0) {
    double l0 = -1e300, l1 = -1e300;
    int e0 = 0, e1 = 0;
    for (int e = 0; e < NEXP; ++e) {
      double v = sm[0][e] + sm[1][e] + sm[2][e] + sm[3][e];
      if (v > l0) { l1 = l0; e1 = e0; l0 = v; e0 = e; }
      else if (v > l1) { l1 = v; e1 = e; }
    }
    double w0 = 1.0 / (1.0 + exp(l1 - l0));
    sel[t * 2 + 0] = e0;
    sel[t * 2 + 1] = e1;
    selw[t * 2 + 0] = (float)w0;
    selw[t * 2 + 1] = (float)(1.0 - w0);
    atomicAdd(&counts[e0], 1);
    atomicAdd(&counts[e1], 1);
  }
}

// ---------------- prefix: 256-aligned per-expert row bases ----------------
__global__ void prefix_kernel(const int* __restrict__ counts, int* __restrict__ rowbase) {
  if (threadIdx.x == 0 && blockIdx.x == 0) {
    int acc = 0;
    for (int e = 0; e < NEXP; ++e) {
      rowbase[e] = acc;
      acc += (counts[e] + 255) & ~255;
    }
    rowbase[NEXP] = acc;  // shared-expert base (dynamic)
  }
}

// ---------------- scatter tokens into packed per-expert row lists ----------------
__global__ __launch_bounds__(256) void scatter_kernel(const int* __restrict__ sel,
                                                      const float* __restrict__ selw,
                                                      const int* __restrict__ rowbase,
                                                      int* __restrict__ cursor,
                                                      int* __restrict__ tok_of_row,
                                                      float* __restrict__ coef_of_row) {
  int idx = blockIdx.x * 256 + threadIdx.x;
  if (idx < T_TOK * 2) {
    int t = idx >> 1;
    int e = sel[idx];
    int slot = atomicAdd(&cursor[e], 1);
    int row = rowbase[e] + slot;
    tok_of_row[row] = t;
    coef_of_row[row] = selw[idx];
  } else if (idx < T_TOK * 3) {
    int t = idx - T_TOK * 2;
    int sb = rowbase[NEXP];
    tok_of_row[sb + t] = t;
    coef_of_row[sb + t] = 1.0f;
  }
}

// =================================================================
// m97-structure grouped GEMM: 256 thr / 4 waves (2x2), tile 128x128, BK=64.
// Single-buffer LDS 33KB -> 4 blocks/CU; 2 barriers/K-step; implicit wave
// overlap (m114) does the pipelining. Per-wave 64x64 (acc[4][4]).
// Swizzle (verified R5, conflicts=0): chunk c -> row=c>>3,
// koff=((c&7)*8)^((r&7)<<3) shorts; read: (ks*32+hi*8)^((row&7)<<3).
// =================================================================

// ---------------- GEMM1: gathered x @ w1e^T + b1e, fused SiLU*mul -> abuf ----------------
// B rows interleaved: even LDS row r -> gate col nt*64+r/2, odd -> up col.
__global__ __launch_bounds__(256, 4) void gemm1_kernel(
    const u16* __restrict__ x_bf, const u16* __restrict__ W1cat,
    const float* __restrict__ b1, const float* __restrict__ sg_b,
    const int* __restrict__ tok_of_row, const int* __restrict__ counts,
    const int* __restrict__ rowbase, u16* __restrict__ abuf) {
  int nt = blockIdx.x, rt = blockIdx.y, e = blockIdx.z;
  int n_e = (e < NEXP) ? counts[e] : T_TOK;
  if (rt * 128 >= n_e) return;
  int rbase = rowbase[e];
  int n_valid = n_e - rt * 128;
  if (n_valid > 128) n_valid = 128;

  __shared__ short As[128 * 64];  // swizzled
  __shared__ short Bs[128 * 64];  // swizzled, g/u interleaved rows
  __shared__ int Ts[128];

  int tid = threadIdx.x;
  if (tid < 128) Ts[tid] = tok_of_row[rbase + rt * 128 + tid];
  __syncthreads();

  int wavebase = tid & 0xC0;
  const u16* srcA[4];
  short* dstA[4];
  const u16* srcB[4];
  short* dstB[4];
#pragma unroll
  for (int p = 0; p < 4; ++p) {
    int c = p * 256 + tid;
    int r = c >> 3;
    int koff = ((c & 7) * 8) ^ ((r & 7) << 3);
    int tok = Ts[r]; if (tok < 0) tok = 0;
    srcA[p] = x_bf + (size_t)tok * H_DIM + koff;
    dstA[p] = &As[(p * 256 + wavebase) * 8];
    int gr = (r & 1) ? (I_DIM + nt * 64 + (r >> 1)) : (nt * 64 + (r >> 1));
    srcB[p] = W1cat + ((size_t)e * (2 * I_DIM) + gr) * H_DIM + koff;
    dstB[p] = &Bs[(p * 256 + wavebase) * 8];
  }

  f32x4 acc[4][4];
#pragma unroll
  for (int m = 0; m < 4; ++m)
#pragma unroll
    for (int n = 0; n < 4; ++n) acc[m][n] = (f32x4){0.f, 0.f, 0.f, 0.f};

  int lane = tid & 63, w = tid >> 6, wr = w >> 1, wc = w & 1;
  int laneq = lane & 15, hi = lane >> 4;

  for (int kt = 0; kt < H_DIM / 64; ++kt) {
    if (kt) __syncthreads();
#pragma unroll
    for (int p = 0; p < 4; ++p) gload16(srcA[p] + kt * 64, dstA[p]);
#pragma unroll
    for (int p = 0; p < 4; ++p) gload16(srcB[p] + kt * 64, dstB[p]);
    __syncthreads();
#pragma unroll
    for (int ks = 0; ks < 2; ++ks) {
      bf16x8 a[4], b[4];
#pragma unroll
      for (int f = 0; f < 4; ++f) {
        int rowA = wr * 64 + f * 16 + laneq;
        int rowB = wc * 64 + f * 16 + laneq;
        a[f] = *(const bf16x8*)(As + rowA * 64 + ((ks * 32 + hi * 8) ^ ((rowA & 7) << 3)));
        b[f] = *(const bf16x8*)(Bs + rowB * 64 + ((ks * 32 + hi * 8) ^ ((rowB & 7) << 3)));
      }
#pragma unroll
      for (int f = 0; f < 4; ++f)
#pragma unroll
        for (int fn = 0; fn < 4; ++fn)
          acc[f][fn] = __builtin_amdgcn_mfma_f32_16x16x32_bf16(a[f], b[fn], acc[f][fn], 0, 0, 0);
    }
  }

  // epilogue: even col = gate, odd col = up (same j); pair via shfl_xor(1)
  const float* bias = (e < NEXP) ? (b1 + (size_t)e * (2 * I_DIM)) : sg_b;
  bool evenl = !(lane & 1);
  float bs[4];
#pragma unroll
  for (int nf = 0; nf < 4; ++nf) {
    int j = (wc * 64 + nf * 16 + laneq) >> 1;
    bs[nf] = evenl ? bias[nt * 64 + j] : bias[I_DIM + nt * 64 + j];
  }
#pragma unroll
  for (int mf = 0; mf < 4; ++mf) {
#pragma unroll
    for (int nf = 0; nf < 4; ++nf) {
      int j = (wc * 64 + nf * 16 + laneq) >> 1;
#pragma unroll
      for (int reg = 0; reg < 4; ++reg) {
        int r = wr * 64 + mf * 16 + hi * 4 + reg;
        float v = acc[mf][nf][reg] + bs[nf];
        float o = __shfl_xor(v, 1);
        if (evenl && r < n_valid) {
          float g = v, u = o;
          float s = g / (1.0f + __expf(-g));
          abuf[(size_t)(rbase + rt * 128 + r) * I_DIM + nt * 64 + j] = f2b(s * u);
        }
      }
    }
  }
}

// ---------------- GEMM2: abuf @ w2e^T * coef -> out ----------------
template <int ATOMIC>
__global__ __launch_bounds__(256, 4) void gemm2_kernel(
    const u16* __restrict__ abuf, const u16* __restrict__ W2cat,
    const int* __restrict__ tok_of_row, const float* __restrict__ coef_of_row,
    const int* __restrict__ counts, const int* __restrict__ rowbase,
    float* __restrict__ out, int e_force) {
  int nt = blockIdx.x, rt = blockIdx.y;
  int e = (e_force >= 0) ? e_force : (int)blockIdx.z;
  int n_e = (e < NEXP) ? counts[e] : T_TOK;
  if (rt * 128 >= n_e) return;
  int rbase = rowbase[e];
  int n_valid = n_e - rt * 128;
  if (n_valid > 128) n_valid = 128;

  __shared__ short As[128 * 64];
  __shared__ short Bs[128 * 64];
  __shared__ int Ts[128];
  __shared__ float Cs[128];

  int tid = threadIdx.x;
  if (tid < 128) {
    int row = rbase + rt * 128 + tid;
    Ts[tid] = tok_of_row[row];
    Cs[tid] = coef_of_row[row];
  }
  __syncthreads();

  int wavebase = tid & 0xC0;
  const u16* srcA[4];
  short* dstA[4];
  const u16* srcB[4];
  short* dstB[4];
#pragma unroll
  for (int p = 0; p < 4; ++p) {
    int c = p * 256 + tid;
    int r = c >> 3;
    int koff = ((c & 7) * 8) ^ ((r & 7) << 3);
    srcA[p] = abuf + (size_t)(rbase + rt * 128 + r) * I_DIM + koff;
    dstA[p] = &As[(p * 256 + wavebase) * 8];
    srcB[p] = W2cat + ((size_t)e * H_DIM + nt * 128 + r) * I_DIM + koff;
    dstB[p] = &Bs[(p * 256 + wavebase) * 8];
  }

  f32x4 acc[4][4];
#pragma unroll
  for (int m = 0; m < 4; ++m)
#pragma unroll
    for (int n = 0; n < 4; ++n) acc[m][n] = (f32x4){0.f, 0.f, 0.f, 0.f};

  int lane = tid & 63, w = tid >> 6, wr = w >> 1, wc = w & 1;
  int laneq = lane & 15, hi = lane >> 4;

  for (int kt = 0; kt < I_DIM / 64; ++kt) {
    if (kt) __syncthreads();
#pragma unroll
    for (int p = 0; p < 4; ++p) gload16(srcA[p] + kt * 64, dstA[p]);
#pragma unroll
    for (int p = 0; p < 4; ++p) gload16(srcB[p] + kt * 64, dstB[p]);
    __syncthreads();
#pragma unroll
    for (int ks = 0; ks < 2; ++ks) {
      bf16x8 a[4], b[4];
#pragma unroll
      for (int f = 0; f < 4; ++f) {
        int rowA = wr * 64 + f * 16 + laneq;
        int rowB = wc * 64 + f * 16 + laneq;
        a[f] = *(const bf16x8*)(As + rowA * 64 + ((ks * 32 + hi * 8) ^ ((rowA & 7) << 3)));
        b[f] = *(const bf16x8*)(Bs + rowB * 64 + ((ks * 32 + hi * 8) ^ ((rowB & 7) << 3)));
      }
#pragma unroll
      for (int f = 0; f < 4; ++f)
#pragma unroll
        for (int fn = 0; fn < 4; ++fn)
          acc[f][fn] = __builtin_amdgcn_mfma_f32_16x16x32_bf16(a[f], b[fn], acc[f][fn], 0, 0, 0);
    }
  }

#pragma unroll
  for (int mf = 0; mf < 4; ++mf) {
#pragma unroll
    for (int nf = 0; nf < 4; ++nf) {
      int col = nt * 128 + wc * 64 + nf * 16 + laneq;
#pragma unroll
      for (int reg = 0; reg < 4; ++reg) {
        int r = wr * 64 + mf * 16 + hi * 4 + reg;
        if (r < n_valid) {
          int tok = Ts[r];
          float val = acc[mf][nf][reg] * Cs[r];
          float* p = out + (size_t)tok * H_DIM + col;
          if (ATOMIC) atomicAdd(p, val);
          else *p = val;
        }
      }
    }
  }
}

// ---------------- launch ----------------
extern "C" void kernel_launch(void* const* d_in, const int* in_sizes, int n_in,
                              void* d_out, int out_size, void* d_ws, size_t ws_size,
                              hipStream_t stream) {
  const float* x    = (const float*)d_in[0];
  const float* gate_w = (const float*)d_in[1];
  const float* w1   = (const float*)d_in[2];
  const float* b1   = (const float*)d_in[3];
  const float* w2   = (const float*)d_in[4];
  const float* sg_w = (const float*)d_in[5];
  const float* sg_b = (const float*)d_in[6];
  const float* sd_w = (const float*)d_in[7];
  float* out = (float*)d_out;

  uint8_t* ws = (uint8_t*)d_ws;
  size_t off = 0;
  auto alloc = [&](size_t bytes) -> void* {
    void* p = ws + off;
    off += (bytes + 255) & ~(size_t)255;
    return p;
  };
  u16*  W1cat = (u16*)alloc((size_t)17 * 2048 * 2048 * 2);
  u16*  W2cat = (u16*)alloc((size_t)17 * 2048 * 1024 * 2);
  u16*  x_bf  = (u16*)alloc((size_t)T_TOK * H_DIM * 2);
  u16*  abuf  = (u16*)alloc((size_t)NROWS * I_DIM * 2);
  int*  tok_of_row  = (int*)alloc((size_t)NROWS * 4);
  float* coef_of_row = (float*)alloc((size_t)NROWS * 4);
  int*  sel   = (int*)alloc((size_t)T_TOK * 2 * 4);
  float* selw = (float*)alloc((size_t)T_TOK * 2 * 4);
  int*  counts  = (int*)alloc(256);
  int*  cursor  = (int*)alloc(256);
  int*  rowbase = (int*)alloc(256);
  (void)ws_size; (void)in_sizes; (void)n_in; (void)out_size;

  hipMemsetAsync(counts, 0, 768, stream);                       // counts+cursor+rowbase
  hipMemsetAsync(tok_of_row, 0xFF, (size_t)NROWS * 4, stream);  // -1 = pad row

  auto cvt = [&](const float* s, u16* d, size_t n) {
    int n4 = (int)(n / 4);
    int blocks = (n4 + 255) / 256;
    if (blocks > 2048) blocks = 2048;
    cvt4_kernel<<<dim3(blocks), dim3(256), 0, stream>>>((const float4*)s, (ushort4*)d, n4);
  };
  cvt(w1,   W1cat, (size_t)16 * 2048 * 2048);
  cvt(sg_w, W1cat + (size_t)16 * 2048 * 2048, (size_t)2048 * 2048);
  cvt(w2,   W2cat, (size_t)16 * 2048 * 1024);
  cvt(sd_w, W2cat + (size_t)16 * 2048 * 1024, (size_t)2048 * 1024);
  cvt(x,    x_bf, (size_t)T_TOK * H_DIM);

  router_kernel<<<dim3(T_TOK), dim3(256), 0, stream>>>(x, gate_w, sel, selw, counts);
  prefix_kernel<<<dim3(1), dim3(64), 0, stream>>>(counts, rowbase);
  scatter_kernel<<<dim3(48), dim3(256), 0, stream>>>(sel, selw, rowbase, cursor, tok_of_row, coef_of_row);

  gemm1_kernel<<<dim3(16, 32, 17), dim3(256), 0, stream>>>(
      x_bf, W1cat, b1, sg_b, tok_of_row, counts, rowbase, abuf);

  // shared expert first: plain stores cover every out element, then routed experts atomicAdd
  gemm2_kernel<0><<<dim3(16, 32, 1), dim3(256), 0, stream>>>(
      abuf, W2cat, tok_of_row, coef_of_row, counts, rowbase, out, NEXP);
  gemm2_kernel<1><<<dim3(16, 32, 16), dim3(256), 0, stream>>>(
      abuf, W2cat, tok_of_row, coef_of_row, counts, rowbase, out, -1);
}

// Round 8
// 523.888 us; speedup vs baseline: 1.3695x; 1.0323x over previous
//
#include <hip/hip_runtime.h>
#include <hip/hip_bf16.h>
#include <stdint.h>

#define T_TOK 4096
#define H_DIM 2048
#define I_DIM 1024
#define NEXP  16
#define NROWS 16384

typedef short bf16x8 __attribute__((ext_vector_type(8)));
typedef float f32x4  __attribute__((ext_vector_type(4)));
typedef unsigned short u16;

__device__ __forceinline__ u16 f2b(float f) {
  union { __hip_bfloat16 h; u16 u; } cv;
  cv.h = __float2bfloat16(f);
  return cv.u;
}

__device__ __forceinline__ void gload16(const void* g, void* l) {
  __builtin_amdgcn_global_load_lds((const __attribute__((address_space(1))) void*)g,
                                   (__attribute__((address_space(3))) void*)l, 16, 0, 0);
}

// ---------------- merged fp32 -> bf16 conversion for all weights ----------------
__global__ __launch_bounds__(256) void cvtall_kernel(
    const float4* __restrict__ w1, const float4* __restrict__ sgw,
    const float4* __restrict__ w2, const float4* __restrict__ sdw,
    ushort4* __restrict__ W1cat, ushort4* __restrict__ W2cat) {
  const int N0 = 16 * 2048 * 2048 / 4;  // w1
  const int N1 = 2048 * 2048 / 4;       // sg_w
  const int N2 = 16 * 2048 * 1024 / 4;  // w2
  const int N3 = 2048 * 1024 / 4;       // sd_w
  const int total = N0 + N1 + N2 + N3;
  int i = blockIdx.x * 256 + threadIdx.x;
  int stride = gridDim.x * 256;
  for (; i < total; i += stride) {
    const float4* s; ushort4* d; int k;
    if (i < N0)            { s = w1;  d = W1cat;      k = i; }
    else if (i < N0 + N1)  { s = sgw; d = W1cat + N0; k = i - N0; }
    else if (i < N0 + N1 + N2) { s = w2; d = W2cat;   k = i - N0 - N1; }
    else                   { s = sdw; d = W2cat + N2; k = i - N0 - N1 - N2; }
    float4 v = s[k];
    ushort4 o;
    o.x = f2b(v.x); o.y = f2b(v.y); o.z = f2b(v.z); o.w = f2b(v.w);
    d[k] = o;
  }
}

// ---------------- router: fp64 logits, top-2, renormalized; also emits x_bf ----------------
__global__ __launch_bounds__(256) void router_kernel(const float* __restrict__ x,
                                                     const float* __restrict__ gw,
                                                     int* __restrict__ sel,
                                                     float* __restrict__ selw,
                                                     int* __restrict__ counts,
                                                     u16* __restrict__ x_bf) {
  int t = blockIdx.x;
  int tid = threadIdx.x;
  const float* xr = x + (size_t)t * H_DIM;
  double p[NEXP];
#pragma unroll
  for (int e = 0; e < NEXP; ++e) p[e] = 0.0;
  bf16x8 xs;
#pragma unroll
  for (int j = 0; j < 8; ++j) {
    int h = tid * 8 + j;
    float xf = xr[h];
    xs[j] = (short)f2b(xf);
    double xv = (double)xf;
#pragma unroll
    for (int e = 0; e < NEXP; ++e) p[e] += xv * (double)gw[e * H_DIM + h];
  }
  *(bf16x8*)(x_bf + (size_t)t * H_DIM + tid * 8) = xs;  // fused x cvt
#pragma unroll
  for (int e = 0; e < NEXP; ++e) {
#pragma unroll
    for (int off = 32; off > 0; off >>= 1) p[e] += __shfl_down(p[e], off);
  }
  __shared__ double sm[4][NEXP];
  int w = tid >> 6;
  if ((tid & 63) == 0) {
#pragma unroll
    for (int e = 0; e < NEXP; ++e) sm[w][e] = p[e];
  }
  __syncthreads();
  if (tid == 0) {
    double l0 = -1e300, l1 = -1e300;
    int e0 = 0, e1 = 0;
    for (int e = 0; e < NEXP; ++e) {
      double v = sm[0][e] + sm[1][e] + sm[2][e] + sm[3][e];
      if (v > l0) { l1 = l0; e1 = e0; l0 = v; e0 = e; }
      else if (v > l1) { l1 = v; e1 = e; }
    }
    double w0 = 1.0 / (1.0 + exp(l1 - l0));
    sel[t * 2 + 0] = e0;
    sel[t * 2 + 1] = e1;
    selw[t * 2 + 0] = (float)w0;
    selw[t * 2 + 1] = (float)(1.0 - w0);
    atomicAdd(&counts[e0], 1);
    atomicAdd(&counts[e1], 1);
  }
}

// ---------------- prefix: 128-aligned per-expert row bases ----------------
__global__ void prefix_kernel(const int* __restrict__ counts, int* __restrict__ rowbase) {
  if (threadIdx.x == 0 && blockIdx.x == 0) {
    int acc = 0;
    for (int e = 0; e < NEXP; ++e) {
      rowbase[e] = acc;
      acc += (counts[e] + 127) & ~127;
    }
    rowbase[NEXP] = acc;  // shared-expert base (dynamic)
  }
}

// ---------------- scatter tokens into packed per-expert row lists ----------------
__global__ __launch_bounds__(256) void scatter_kernel(const int* __restrict__ sel,
                                                      const float* __restrict__ selw,
                                                      const int* __restrict__ rowbase,
                                                      int* __restrict__ cursor,
                                                      int* __restrict__ tok_of_row,
                                                      float* __restrict__ coef_of_row) {
  int idx = blockIdx.x * 256 + threadIdx.x;
  if (idx < T_TOK * 2) {
    int t = idx >> 1;
    int e = sel[idx];
    int slot = atomicAdd(&cursor[e], 1);
    int row = rowbase[e] + slot;
    tok_of_row[row] = t;
    coef_of_row[row] = selw[idx];
  } else if (idx < T_TOK * 3) {
    int t = idx - T_TOK * 2;
    int sb = rowbase[NEXP];
    tok_of_row[sb + t] = t;
    coef_of_row[sb + t] = 1.0f;
  }
}

// =================================================================
// m97-structure grouped GEMM: 256 thr / 4 waves (2x2), tile 128x128, BK=64.
// Single-buffer LDS 33KB -> 4 blocks/CU; 2 barriers/K-step.
// Swizzle (verified, conflicts=0): chunk c -> row=c>>3,
// koff=((c&7)*8)^((r&7)<<3) shorts; read: (ks*32+hi*8)^((row&7)<<3).
// =================================================================

// ---------------- GEMM1: gathered x @ w1e^T + b1e, fused SiLU*mul -> abuf ----------------
// B tile: rows [0,64) = gate cols nt*64..+63, rows [64,128) = up cols nt*64..+63.
// Wave n-frags 0-1 = gate, 2-3 = up at SAME output cols -> lane-local silu(g)*u.
__global__ __launch_bounds__(256, 4) void gemm1_kernel(
    const u16* __restrict__ x_bf, const u16* __restrict__ W1cat,
    const float* __restrict__ b1, const float* __restrict__ sg_b,
    const int* __restrict__ tok_of_row, const int* __restrict__ counts,
    const int* __restrict__ rowbase, u16* __restrict__ abuf) {
  int nt = blockIdx.x, rt = blockIdx.y, e = blockIdx.z;
  int n_e = (e < NEXP) ? counts[e] : T_TOK;
  if (rt * 128 >= n_e) return;
  int rbase = rowbase[e];
  int n_valid = n_e - rt * 128;
  if (n_valid > 128) n_valid = 128;

  __shared__ short As[128 * 64];  // swizzled
  __shared__ short Bs[128 * 64];  // swizzled, rows 0-63 gate / 64-127 up
  __shared__ int Ts[128];

  int tid = threadIdx.x;
  if (tid < 128) Ts[tid] = tok_of_row[rbase + rt * 128 + tid];
  __syncthreads();

  int wavebase = tid & 0xC0;
  const u16* srcA[4];
  short* dstA[4];
  const u16* srcB[4];
  short* dstB[4];
#pragma unroll
  for (int p = 0; p < 4; ++p) {
    int c = p * 256 + tid;
    int r = c >> 3;
    int koff = ((c & 7) * 8) ^ ((r & 7) << 3);
    int tok = Ts[r]; if (tok < 0) tok = 0;
    srcA[p] = x_bf + (size_t)tok * H_DIM + koff;
    dstA[p] = &As[(p * 256 + wavebase) * 8];
    int gr = (r < 64) ? (nt * 64 + r) : (I_DIM + nt * 64 + (r - 64));
    srcB[p] = W1cat + ((size_t)e * (2 * I_DIM) + gr) * H_DIM + koff;
    dstB[p] = &Bs[(p * 256 + wavebase) * 8];
  }

  f32x4 acc[4][4];
#pragma unroll
  for (int m = 0; m < 4; ++m)
#pragma unroll
    for (int n = 0; n < 4; ++n) acc[m][n] = (f32x4){0.f, 0.f, 0.f, 0.f};

  int lane = tid & 63, w = tid >> 6, wr = w >> 1, wc = w & 1;
  int laneq = lane & 15, hi = lane >> 4;

  for (int kt = 0; kt < H_DIM / 64; ++kt) {
    if (kt) __syncthreads();
#pragma unroll
    for (int p = 0; p < 4; ++p) gload16(srcA[p] + kt * 64, dstA[p]);
#pragma unroll
    for (int p = 0; p < 4; ++p) gload16(srcB[p] + kt * 64, dstB[p]);
    __syncthreads();
#pragma unroll
    for (int ks = 0; ks < 2; ++ks) {
      bf16x8 a[4], b[4];
#pragma unroll
      for (int f = 0; f < 4; ++f) {
        int rowA = wr * 64 + f * 16 + laneq;
        a[f] = *(const bf16x8*)(As + rowA * 64 + ((ks * 32 + hi * 8) ^ ((rowA & 7) << 3)));
        int rowB = ((f < 2) ? (wc * 32 + f * 16) : (64 + wc * 32 + (f - 2) * 16)) + laneq;
        b[f] = *(const bf16x8*)(Bs + rowB * 64 + ((ks * 32 + hi * 8) ^ ((rowB & 7) << 3)));
      }
#pragma unroll
      for (int f = 0; f < 4; ++f)
#pragma unroll
        for (int fn = 0; fn < 4; ++fn)
          acc[f][fn] = __builtin_amdgcn_mfma_f32_16x16x32_bf16(a[f], b[fn], acc[f][fn], 0, 0, 0);
    }
  }

  // epilogue: lane-local silu(g)*u; all 64 lanes store
  const float* bias = (e < NEXP) ? (b1 + (size_t)e * (2 * I_DIM)) : sg_b;
#pragma unroll
  for (int nf = 0; nf < 2; ++nf) {
    int j = nt * 64 + wc * 32 + nf * 16 + laneq;
    float bg = bias[j];
    float bu = bias[I_DIM + j];
#pragma unroll
    for (int mf = 0; mf < 4; ++mf) {
#pragma unroll
      for (int reg = 0; reg < 4; ++reg) {
        int r = wr * 64 + mf * 16 + hi * 4 + reg;
        if (r < n_valid) {
          float g = acc[mf][nf][reg] + bg;
          float u = acc[mf][nf + 2][reg] + bu;
          float s = g / (1.0f + __expf(-g));
          abuf[(size_t)(rbase + rt * 128 + r) * I_DIM + j] = f2b(s * u);
        }
      }
    }
  }
}

// ---------------- GEMM2: abuf @ w2e^T * coef -> out ----------------
template <int ATOMIC>
__global__ __launch_bounds__(256, 4) void gemm2_kernel(
    const u16* __restrict__ abuf, const u16* __restrict__ W2cat,
    const int* __restrict__ tok_of_row, const float* __restrict__ coef_of_row,
    const int* __restrict__ counts, const int* __restrict__ rowbase,
    float* __restrict__ out, int e_force) {
  int nt = blockIdx.x, rt = blockIdx.y;
  int e = (e_force >= 0) ? e_force : (int)blockIdx.z;
  int n_e = (e < NEXP) ? counts[e] : T_TOK;
  if (rt * 128 >= n_e) return;
  int rbase = rowbase[e];
  int n_valid = n_e - rt * 128;
  if (n_valid > 128) n_valid = 128;

  __shared__ short As[128 * 64];
  __shared__ short Bs[128 * 64];
  __shared__ int Ts[128];
  __shared__ float Cs[128];

  int tid = threadIdx.x;
  if (tid < 128) {
    int row = rbase + rt * 128 + tid;
    Ts[tid] = tok_of_row[row];
    Cs[tid] = coef_of_row[row];
  }
  __syncthreads();

  int wavebase = tid & 0xC0;
  const u16* srcA[4];
  short* dstA[4];
  const u16* srcB[4];
  short* dstB[4];
#pragma unroll
  for (int p = 0; p < 4; ++p) {
    int c = p * 256 + tid;
    int r = c >> 3;
    int koff = ((c & 7) * 8) ^ ((r & 7) << 3);
    srcA[p] = abuf + (size_t)(rbase + rt * 128 + r) * I_DIM + koff;
    dstA[p] = &As[(p * 256 + wavebase) * 8];
    srcB[p] = W2cat + ((size_t)e * H_DIM + nt * 128 + r) * I_DIM + koff;
    dstB[p] = &Bs[(p * 256 + wavebase) * 8];
  }

  f32x4 acc[4][4];
#pragma unroll
  for (int m = 0; m < 4; ++m)
#pragma unroll
    for (int n = 0; n < 4; ++n) acc[m][n] = (f32x4){0.f, 0.f, 0.f, 0.f};

  int lane = tid & 63, w = tid >> 6, wr = w >> 1, wc = w & 1;
  int laneq = lane & 15, hi = lane >> 4;

  for (int kt = 0; kt < I_DIM / 64; ++kt) {
    if (kt) __syncthreads();
#pragma unroll
    for (int p = 0; p < 4; ++p) gload16(srcA[p] + kt * 64, dstA[p]);
#pragma unroll
    for (int p = 0; p < 4; ++p) gload16(srcB[p] + kt * 64, dstB[p]);
    __syncthreads();
#pragma unroll
    for (int ks = 0; ks < 2; ++ks) {
      bf16x8 a[4], b[4];
#pragma unroll
      for (int f = 0; f < 4; ++f) {
        int rowA = wr * 64 + f * 16 + laneq;
        int rowB = wc * 64 + f * 16 + laneq;
        a[f] = *(const bf16x8*)(As + rowA * 64 + ((ks * 32 + hi * 8) ^ ((rowA & 7) << 3)));
        b[f] = *(const bf16x8*)(Bs + rowB * 64 + ((ks * 32 + hi * 8) ^ ((rowB & 7) << 3)));
      }
#pragma unroll
      for (int f = 0; f < 4; ++f)
#pragma unroll
        for (int fn = 0; fn < 4; ++fn)
          acc[f][fn] = __builtin_amdgcn_mfma_f32_16x16x32_bf16(a[f], b[fn], acc[f][fn], 0, 0, 0);
    }
  }

#pragma unroll
  for (int mf = 0; mf < 4; ++mf) {
#pragma unroll
    for (int nf = 0; nf < 4; ++nf) {
      int col = nt * 128 + wc * 64 + nf * 16 + laneq;
#pragma unroll
      for (int reg = 0; reg < 4; ++reg) {
        int r = wr * 64 + mf * 16 + hi * 4 + reg;
        if (r < n_valid) {
          int tok = Ts[r];
          float val = acc[mf][nf][reg] * Cs[r];
          float* p = out + (size_t)tok * H_DIM + col;
          if (ATOMIC) atomicAdd(p, val);
          else *p = val;
        }
      }
    }
  }
}

// ---------------- launch ----------------
extern "C" void kernel_launch(void* const* d_in, const int* in_sizes, int n_in,
                              void* d_out, int out_size, void* d_ws, size_t ws_size,
                              hipStream_t stream) {
  const float* x    = (const float*)d_in[0];
  const float* gate_w = (const float*)d_in[1];
  const float* w1   = (const float*)d_in[2];
  const float* b1   = (const float*)d_in[3];
  const float* w2   = (const float*)d_in[4];
  const float* sg_w = (const float*)d_in[5];
  const float* sg_b = (const float*)d_in[6];
  const float* sd_w = (const float*)d_in[7];
  float* out = (float*)d_out;

  uint8_t* ws = (uint8_t*)d_ws;
  size_t off = 0;
  auto alloc = [&](size_t bytes) -> void* {
    void* p = ws + off;
    off += (bytes + 255) & ~(size_t)255;
    return p;
  };
  u16*  W1cat = (u16*)alloc((size_t)17 * 2048 * 2048 * 2);
  u16*  W2cat = (u16*)alloc((size_t)17 * 2048 * 1024 * 2);
  u16*  x_bf  = (u16*)alloc((size_t)T_TOK * H_DIM * 2);
  u16*  abuf  = (u16*)alloc((size_t)NROWS * I_DIM * 2);
  int*  tok_of_row  = (int*)alloc((size_t)NROWS * 4);
  float* coef_of_row = (float*)alloc((size_t)NROWS * 4);
  int*  sel   = (int*)alloc((size_t)T_TOK * 2 * 4);
  float* selw = (float*)alloc((size_t)T_TOK * 2 * 4);
  int*  counts  = (int*)alloc(256);
  int*  cursor  = (int*)alloc(256);
  int*  rowbase = (int*)alloc(256);
  (void)ws_size; (void)in_sizes; (void)n_in; (void)out_size;

  hipMemsetAsync(counts, 0, 768, stream);                       // counts+cursor+rowbase
  hipMemsetAsync(tok_of_row, 0xFF, (size_t)NROWS * 4, stream);  // -1 = pad row

  cvtall_kernel<<<dim3(3072), dim3(256), 0, stream>>>(
      (const float4*)w1, (const float4*)sg_w, (const float4*)w2, (const float4*)sd_w,
      (ushort4*)W1cat, (ushort4*)W2cat);

  router_kernel<<<dim3(T_TOK), dim3(256), 0, stream>>>(x, gate_w, sel, selw, counts, x_bf);
  prefix_kernel<<<dim3(1), dim3(64), 0, stream>>>(counts, rowbase);
  scatter_kernel<<<dim3(48), dim3(256), 0, stream>>>(sel, selw, rowbase, cursor, tok_of_row, coef_of_row);

  gemm1_kernel<<<dim3(16, 32, 17), dim3(256), 0, stream>>>(
      x_bf, W1cat, b1, sg_b, tok_of_row, counts, rowbase, abuf);

  // shared expert first: plain stores cover every out element, then routed experts atomicAdd
  gemm2_kernel<0><<<dim3(16, 32, 1), dim3(256), 0, stream>>>(
      abuf, W2cat, tok_of_row, coef_of_row, counts, rowbase, out, NEXP);
  gemm2_kernel<1><<<dim3(16, 32, 16), dim3(256), 0, stream>>>(
      abuf, W2cat, tok_of_row, coef_of_row, counts, rowbase, out, -1);
}